// Round 3
// baseline (330.173 us; speedup 1.0000x reference)
//
#include <hip/hip_runtime.h>
#include <hip/hip_bf16.h>
#include <math.h>

// ---- problem constants (fixed by setup_inputs) ----
constexpr int B   = 4;
constexpr int S   = 4096;
constexpr int D   = 64;
constexpr int NH  = 8;        // hash rounds
constexpr int NB  = 64;       // buckets per hash
constexpr int NBT = 512;      // total buckets = NH*NB
constexpr int NI  = NH * S;   // items per batch = 32768
constexpr int NCH = 512;      // chunks per batch (of 64)
constexpr int CHB = 256;      // sort chunks per batch (of 128)

typedef __attribute__((ext_vector_type(8))) short bf16x8;
typedef __attribute__((ext_vector_type(4))) float f32x4;

__device__ __forceinline__ unsigned short bf_rne(float x) {
    unsigned u = __float_as_uint(x);
    u += 0x7fffu + ((u >> 16) & 1u);
    return (unsigned short)(u >> 16);
}
__device__ __forceinline__ float bf_tof(unsigned short h) {
    return __uint_as_float(((unsigned)h) << 16);
}

// ============================================================
// K0: prep — q16 = bf16(q/8), kn16 = bf16(k/||k||), vhl = (hi|lo<<16) of v
// grid: B*S/4 blocks, 256 threads (4 rows x 64 lanes)
// ============================================================
__global__ void k_prep(const float* __restrict__ q, const float* __restrict__ k,
                       const float* __restrict__ v, unsigned short* __restrict__ q16,
                       unsigned short* __restrict__ kn16, unsigned* __restrict__ vhl) {
    int row  = blockIdx.x * 4 + (threadIdx.x >> 6);
    int lane = threadIdx.x & 63;
    size_t idx = (size_t)row * 64 + lane;
    float kv = k[idx];
    float ss = kv * kv;
#pragma unroll
    for (int m = 1; m < 64; m <<= 1) ss += __shfl_xor(ss, m, 64);
    kn16[idx] = bf_rne(kv / sqrtf(ss));
    q16[idx]  = bf_rne(q[idx] * 0.125f);
    float vv = v[idx];
    unsigned short h = bf_rne(vv);
    unsigned short l = bf_rne(vv - bf_tof(h));
    vhl[idx] = (unsigned)h | ((unsigned)l << 16);
}

// ============================================================
// K1: LSH hashing (register-tiled GEMM + argmax) + fused histogram
// grid: B*NH*32 = 1024 blocks, 256 threads; block covers 128 tokens
// ============================================================
__global__ __launch_bounds__(256)
void k_hash(const float* __restrict__ q, const float* __restrict__ rot,
            int* __restrict__ buckets, int* __restrict__ counts) {
    int blk = blockIdx.x;
    int tko = blk & 31, h = (blk >> 5) & 7, b = blk >> 8;
    __shared__ __align__(16) float rs[64 * 36];   // [d][n] padded
    __shared__ int hist[64];
    if (threadIdx.x < 64) hist[threadIdx.x] = 0;
    for (int i = threadIdx.x; i < 2048; i += 256) {
        int nn = i & 31, d = i >> 5;
        rs[d * 36 + nn] = rot[(d * 8 + h) * 32 + nn];
    }
    __syncthreads();
    int tid = threadIdx.x;
    int ng = tid & 7, tg = tid >> 3;
    int t0 = tko * 128 + tg * 4;
    const float* qp = q + ((size_t)b * S + t0) * 64;
    float acc[4][4] = {};
    #pragma unroll 4
    for (int d4 = 0; d4 < 16; ++d4) {
        f32x4 r4[4];
        #pragma unroll
        for (int dd = 0; dd < 4; ++dd)
            r4[dd] = *(const f32x4*)(rs + (4 * d4 + dd) * 36 + 4 * ng);
        #pragma unroll
        for (int i = 0; i < 4; ++i) {
            f32x4 q4 = *(const f32x4*)(qp + i * 64 + d4 * 4);
            #pragma unroll
            for (int dd = 0; dd < 4; ++dd)
                #pragma unroll
                for (int c = 0; c < 4; ++c)
                    acc[i][c] += q4[dd] * r4[dd][c];
        }
    }
    #pragma unroll
    for (int i = 0; i < 4; ++i) {
        float vp = -3.402823466e38f, vn = -3.402823466e38f;
        int ip = 0, in_ = 0;
        #pragma unroll
        for (int c = 0; c < 4; ++c) {
            float a = acc[i][c]; int idx = 4 * ng + c;
            if (a > vp)  { vp = a;  ip = idx; }
            if (-a > vn) { vn = -a; in_ = idx; }
        }
        #pragma unroll
        for (int off = 1; off < 8; off <<= 1) {
            float ov = __shfl_xor(vp, off); int oi = __shfl_xor(ip, off);
            if (ov > vp || (ov == vp && oi < ip)) { vp = ov; ip = oi; }
            ov = __shfl_xor(vn, off); oi = __shfl_xor(in_, off);
            if (ov > vn || (ov == vn && oi < in_)) { vn = ov; in_ = oi; }
        }
        if (ng == 0) {
            int bi = (vn > vp) ? (in_ + 32) : ip;   // tie -> positive half
            buckets[b * NI + h * 4096 + t0 + i] = bi + h * NB;
            atomicAdd(&hist[bi], 1);
        }
    }
    __syncthreads();
    int cglob = h * 32 + tko;
    int* cw = counts + ((size_t)b * CHB + cglob) * NBT;
    for (int j = tid; j < NBT; j += 256) {
        int local = j - h * 64;
        cw[j] = (local >= 0 && local < 64) ? hist[local] : 0;
    }
}

// ============================================================
// K3a: per-(b,bucket) scan over 256 chunks (wave scan, 4/lane)
// grid: B*NBT = 2048 blocks, 64 threads
// ============================================================
__global__ void k_scan1(int* __restrict__ counts, int* __restrict__ tot) {
    int bkt = blockIdx.x & 511, b = blockIdx.x >> 9;
    int lane = threadIdx.x;
    size_t i0 = ((size_t)b * CHB + 4 * lane) * NBT + bkt;
    int v0 = counts[i0], v1 = counts[i0 + NBT], v2 = counts[i0 + 2 * NBT], v3 = counts[i0 + 3 * NBT];
    int s = v0 + v1 + v2 + v3;
    int incl = s;
    #pragma unroll
    for (int off = 1; off < 64; off <<= 1) {
        int t = __shfl_up(incl, off);
        if (lane >= off) incl += t;
    }
    int excl = incl - s;
    counts[i0]           = excl;
    counts[i0 + NBT]     = excl + v0;
    counts[i0 + 2 * NBT] = excl + v0 + v1;
    counts[i0 + 3 * NBT] = excl + v0 + v1 + v2;
    if (lane == 63) tot[b * NBT + bkt] = incl;
}

// ============================================================
// K3b: cross-bucket exclusive scan (per batch)
// ============================================================
__global__ void k_scan2(const int* __restrict__ tot, int* __restrict__ base) {
    int b = blockIdx.x, bkt = threadIdx.x;
    __shared__ int bufA[NBT], bufB[NBT];
    int run = tot[b * NBT + bkt];
    bufA[bkt] = run;
    __syncthreads();
    int* src = bufA; int* dst = bufB;
    for (int off = 1; off < NBT; off <<= 1) {
        int x = src[bkt] + ((bkt >= off) ? src[bkt - off] : 0);
        dst[bkt] = x;
        __syncthreads();
        int* tsw = src; src = dst; dst = tsw;
    }
    base[b * NBT + bkt] = src[bkt] - run;
}

// ============================================================
// K4: stable scatter — packed sorted meta + inverse perm + locsT
// grid: B*CHB = 1024 blocks, 128 threads
// ============================================================
__global__ void k_scatter(const int* __restrict__ buckets, const int* __restrict__ counts,
                          const int* __restrict__ base, int* __restrict__ spos,
                          int* __restrict__ undo, int* __restrict__ locsT) {
    int b = blockIdx.x >> 8, c = blockIdx.x & 255;
    __shared__ int bk_s[128];
    int i_loc  = threadIdx.x;
    int i_flat = c * 128 + i_loc;
    int bkt = buckets[b * NI + i_flat];
    bk_s[i_loc] = bkt;
    __syncthreads();
    int rank = 0;
    for (int j = 0; j < 128; ++j) {
        int vv = bk_s[j];
        rank += (j < i_loc && vv == bkt);
    }
    int pos = base[b * NBT + bkt] + counts[((size_t)b * CHB + c) * NBT + bkt] + rank;
    spos[b * NI + pos] = (i_flat & 4095) | (bkt << 12);   // t | bkt<<12
    undo[b * NI + i_flat] = pos;
    int h = i_flat >> 12, t = i_flat & 4095;
    locsT[(((size_t)b << 12) | t) * 8 + h] = bkt * NCH + (pos >> 6);
}

// ============================================================
// K6: chunked attention via MFMA (64 q rows x 128 keys, d=64)
//   LDS overlay: qs/ks (phase B/C) -> ph/pl + vh/vl (phase E/F)
//   3 blocks/CU (54 KB LDS)
// ============================================================
__global__ __launch_bounds__(256, 3)
void k_attn(const unsigned short* __restrict__ q16, const unsigned short* __restrict__ kn16,
            const unsigned* __restrict__ vhl, const int* __restrict__ spos,
            const int* __restrict__ locsT, float* __restrict__ so,
            float* __restrict__ slog) {
    int n = blockIdx.x & 511, b = blockIdx.x >> 9;
    __shared__ __align__(16) char buf[54016];
    unsigned short* qs = (unsigned short*)buf;            // [64][72] bf16
    unsigned short* ks = (unsigned short*)(buf + 9216);   // [128][72] bf16
    unsigned short* ph = (unsigned short*)buf;            // [64][72] overlay
    unsigned short* pl = (unsigned short*)(buf + 9216);   // [64][72] overlay
    unsigned short* vh = (unsigned short*)(buf + 18432);  // [64][136] v^T hi (overlays ks tail)
    unsigned short* vl = (unsigned short*)(buf + 35840);  // [64][136] v^T lo
    int* mq = (int*)(buf + 53248);                        // [64]  t|bkt<<12
    int* mk = (int*)(buf + 53504);                        // [128]

    int tid = threadIdx.x;
    int bni = b * NI;
    const unsigned short* q16b = q16 + ((size_t)b << 12) * 64;
    const unsigned short* kn16b = kn16 + ((size_t)b << 12) * 64;
    const unsigned* vhlb = vhl + ((size_t)b << 12) * 64;

    // ---- phase A: sorted-position metadata ----
    if (tid < 64) mq[tid] = spos[bni + n * 64 + tid];
    else if (tid < 192) {
        int z = tid - 64;
        int nn = (z < 64) ? n : ((n + 511) & 511);   // z>=64: previous chunk
        mk[z] = spos[bni + nn * 64 + (z & 63)];
    }
    __syncthreads();

    // ---- phase B: stage q/k tiles (pure copies), prefetch v to regs ----
    #pragma unroll
    for (int it = 0; it < 2; ++it) {                  // q: 512 16B-chunks
        int i = it * 256 + tid;
        int row = i >> 3, c8 = i & 7;
        int t = mq[row] & 4095;
        uint4 val = *(const uint4*)(q16b + (size_t)t * 64 + c8 * 8);
        *(uint4*)(qs + row * 72 + c8 * 8) = val;
    }
    #pragma unroll
    for (int it = 0; it < 4; ++it) {                  // k: 1024 16B-chunks
        int i = it * 256 + tid;
        int row = i >> 3, c8 = i & 7;
        int t = mk[row] & 4095;
        uint4 val = *(const uint4*)(kn16b + (size_t)t * 64 + c8 * 8);
        *(uint4*)(ks + row * 72 + c8 * 8) = val;
    }
    unsigned u0[16], u1[16];
    #pragma unroll
    for (int it = 0; it < 16; ++it) {                 // v gather-prefetch
        int i = it * 256 + tid;
        int d  = (i & 7) | (((i >> 8) & 7) << 3);
        int zp = ((i >> 3) & 31) | (((i >> 11) & 1) << 5);
        int t0 = mk[2 * zp] & 4095, t1 = mk[2 * zp + 1] & 4095;
        u0[it] = vhlb[(size_t)t0 * 64 + d];
        u1[it] = vhlb[(size_t)t1 * 64 + d];
    }
    __syncthreads();

    int li = tid & 15, hi4 = (tid >> 4) & 3, w = tid >> 6;

    // ---- phase C: QK^T via MFMA ----
    f32x4 sacc[8];
    {
        bf16x8 a0 = *(bf16x8*)(qs + (16 * w + li) * 72 + 8 * hi4);
        bf16x8 a1 = *(bf16x8*)(qs + (16 * w + li) * 72 + 32 + 8 * hi4);
        #pragma unroll
        for (int zt = 0; zt < 8; ++zt) {
            bf16x8 b0 = *(bf16x8*)(ks + (16 * zt + li) * 72 + 8 * hi4);
            bf16x8 b1 = *(bf16x8*)(ks + (16 * zt + li) * 72 + 32 + 8 * hi4);
            f32x4 c = {0.f, 0.f, 0.f, 0.f};
            c = __builtin_amdgcn_mfma_f32_16x16x32_bf16(a0, b0, c, 0, 0, 0);
            c = __builtin_amdgcn_mfma_f32_16x16x32_bf16(a1, b1, c, 0, 0, 0);
            sacc[zt] = c;
        }
    }

    // ---- phase D: masks + dup correction + softmax ----
    int tqr[4], bqr[4], lqr[4][8];
    #pragma unroll
    for (int j = 0; j < 4; ++j) {
        int R = 16 * w + 4 * hi4 + j;
        int m = mq[R];
        tqr[j] = m & 4095; bqr[j] = m >> 12;
        const int4* lp = (const int4*)(locsT + (((size_t)b << 12) | tqr[j]) * 8);
        int4 A = lp[0], Bv = lp[1];
        lqr[j][0] = A.x;  lqr[j][1] = A.y;  lqr[j][2] = A.z;  lqr[j][3] = A.w;
        lqr[j][4] = Bv.x; lqr[j][5] = Bv.y; lqr[j][6] = Bv.z; lqr[j][7] = Bv.w;
    }
    #pragma unroll
    for (int zt = 0; zt < 8; ++zt) {
        int z = 16 * zt + li;
        int mz = mk[z]; int tk = mz & 4095, bk = mz >> 12;
        const int4* lp = (const int4*)(locsT + (((size_t)b << 12) | tk) * 8);
        int4 A = lp[0], Bv = lp[1];
        int l1[8] = {A.x, A.y, A.z, A.w, Bv.x, Bv.y, Bv.z, Bv.w};
        int l2[8];
        #pragma unroll
        for (int h = 0; h < 8; ++h) l2[h] = (l1[h] & ~511) | ((l1[h] + 1) & 511);
        #pragma unroll
        for (int j = 0; j < 4; ++j) {
            float s = sacc[zt][j];
            if (tqr[j] == tk) s = -10000.0f;
            if (bqr[j] != bk) s = -3.402823466e38f;
            int dup = 0;
            #pragma unroll
            for (int h = 0; h < 8; ++h)
                dup += (int)(lqr[j][h] == l1[h]) + (int)(lqr[j][h] == l2[h]);
            s -= __logf((float)dup + 1e-9f);
            sacc[zt][j] = s;
        }
    }

    float inv[4];
    #pragma unroll
    for (int j = 0; j < 4; ++j) {
        float m = sacc[0][j];
        #pragma unroll
        for (int zt = 1; zt < 8; ++zt) m = fmaxf(m, sacc[zt][j]);
        #pragma unroll
        for (int off = 1; off < 16; off <<= 1) m = fmaxf(m, __shfl_xor(m, off));
        float sum = 0.f;
        #pragma unroll
        for (int zt = 0; zt < 8; ++zt) {
            float e = __expf(sacc[zt][j] - m);
            sacc[zt][j] = e; sum += e;
        }
        #pragma unroll
        for (int off = 1; off < 16; off <<= 1) sum += __shfl_xor(sum, off);
        float lse = m + __logf(sum);
        inv[j] = 1.0f / sum;
        if (li == 0) slog[bni + n * 64 + 16 * w + 4 * hi4 + j] = lse;
    }
    __syncthreads();   // all qs/ks reads done before overlays

    // ---- phase E0: write V (from regs) + P half 0 ----
    #pragma unroll
    for (int it = 0; it < 16; ++it) {
        int i = it * 256 + tid;
        int d  = (i & 7) | (((i >> 8) & 7) << 3);
        int zp = ((i >> 3) & 31) | (((i >> 11) & 1) << 5);
        unsigned a = u0[it], c = u1[it];
        *(unsigned*)(vh + d * 136 + 2 * zp) = (a & 0xffffu) | (c << 16);
        *(unsigned*)(vl + d * 136 + 2 * zp) = (a >> 16) | (c & 0xffff0000u);
    }
    f32x4 oacc[4] = {{0,0,0,0},{0,0,0,0},{0,0,0,0},{0,0,0,0}};
    #pragma unroll
    for (int half = 0; half < 2; ++half) {
        #pragma unroll
        for (int zt4 = 0; zt4 < 4; ++zt4) {
            int zt = half * 4 + zt4;
            #pragma unroll
            for (int j = 0; j < 4; ++j) {
                float p  = sacc[zt][j] * inv[j];
                float po = __shfl_xor(p, 1);
                if ((li & 1) == 0) {
                    int R  = 16 * w + 4 * hi4 + j;
                    int zl = 16 * zt4 + li;   // even
                    unsigned short h0 = bf_rne(p), h1 = bf_rne(po);
                    *(unsigned*)(ph + R * 72 + zl) = (unsigned)h0 | ((unsigned)h1 << 16);
                    unsigned short g0 = bf_rne(p - bf_tof(h0)), g1 = bf_rne(po - bf_tof(h1));
                    *(unsigned*)(pl + R * 72 + zl) = (unsigned)g0 | ((unsigned)g1 << 16);
                }
            }
        }
        __syncthreads();
        #pragma unroll
        for (int step = 0; step < 2; ++step) {
            bf16x8 pa = *(bf16x8*)(ph + (16 * w + li) * 72 + 32 * step + 8 * hi4);
            bf16x8 pb = *(bf16x8*)(pl + (16 * w + li) * 72 + 32 * step + 8 * hi4);
            #pragma unroll
            for (int nt = 0; nt < 4; ++nt) {
                bf16x8 vb = *(bf16x8*)(vh + (16 * nt + li) * 136 + 64 * half + 32 * step + 8 * hi4);
                bf16x8 vc = *(bf16x8*)(vl + (16 * nt + li) * 136 + 64 * half + 32 * step + 8 * hi4);
                oacc[nt] = __builtin_amdgcn_mfma_f32_16x16x32_bf16(pa, vb, oacc[nt], 0, 0, 0);
                oacc[nt] = __builtin_amdgcn_mfma_f32_16x16x32_bf16(pb, vb, oacc[nt], 0, 0, 0);
                oacc[nt] = __builtin_amdgcn_mfma_f32_16x16x32_bf16(pa, vc, oacc[nt], 0, 0, 0);
            }
        }
        __syncthreads();
    }

    // ---- epilogue ----
    size_t ob = ((size_t)bni + n * 64) * 64;
    #pragma unroll
    for (int nt = 0; nt < 4; ++nt)
        #pragma unroll
        for (int j = 0; j < 4; ++j)
            so[ob + (size_t)(16 * w + 4 * hi4 + j) * 64 + 16 * nt + li] = oacc[nt][j];
}

// ============================================================
// K7: unsort + combine across hash rounds
// ============================================================
__global__ void k_comb(const int* __restrict__ undo, const float* __restrict__ slog,
                       const float* __restrict__ so, float* __restrict__ out) {
    int flatT = blockIdx.x * 4 + (threadIdx.x >> 6);
    int lane  = threadIdx.x & 63;
    int b = flatT >> 12, t = flatT & (S - 1);
    int ph[NH]; float lg[NH];
    float m = -3.402823466e38f;
#pragma unroll
    for (int h = 0; h < NH; ++h) {
        ph[h] = undo[b * NI + (h << 12) + t];
        lg[h] = slog[b * NI + ph[h]];
        m = fmaxf(m, lg[h]);
    }
    float sum = 0.f;
#pragma unroll
    for (int h = 0; h < NH; ++h) sum += __expf(lg[h] - m);
    float lse2 = m + __logf(sum);
    float o = 0.f;
#pragma unroll
    for (int h = 0; h < NH; ++h) {
        float wgt = __expf(lg[h] - lse2);
        o += wgt * so[((size_t)b * NI + ph[h]) * D + lane];
    }
    out[(size_t)flatT * D + lane] = o;
}

// ============================================================
extern "C" void kernel_launch(void* const* d_in, const int* in_sizes, int n_in,
                              void* d_out, int out_size, void* d_ws, size_t ws_size,
                              hipStream_t stream) {
    const float* q   = (const float*)d_in[0];
    const float* k   = (const float*)d_in[1];
    const float* v   = (const float*)d_in[2];
    const float* rot = (const float*)d_in[3];
    float* out = (float*)d_out;

    char* ws = (char*)d_ws;
    size_t off = 0;
    auto alloc = [&](size_t bytes) -> void* {
        void* p = ws + off;
        off += (bytes + 255) & ~(size_t)255;
        return p;
    };
    unsigned short* q16  = (unsigned short*)alloc((size_t)B * S * D * 2);
    unsigned short* kn16 = (unsigned short*)alloc((size_t)B * S * D * 2);
    unsigned*       vhl  = (unsigned*)alloc((size_t)B * S * D * 4);
    float* so      = (float*)alloc((size_t)B * NI * D * 4);
    float* slog    = (float*)alloc((size_t)B * NI * 4);
    int*   buckets = (int*)alloc((size_t)B * NI * 4);
    int*   counts  = (int*)alloc((size_t)B * CHB * NBT * 4);
    int*   tot     = (int*)alloc((size_t)B * NBT * 4);
    int*   base    = (int*)alloc((size_t)B * NBT * 4);
    int*   spos    = (int*)alloc((size_t)B * NI * 4);
    int*   undo    = (int*)alloc((size_t)B * NI * 4);
    int*   locsT   = (int*)alloc((size_t)B * S * NH * 4);

    k_prep<<<B * S / 4, 256, 0, stream>>>(q, k, v, q16, kn16, vhl);
    k_hash<<<1024, 256, 0, stream>>>(q, rot, buckets, counts);
    k_scan1<<<B * NBT, 64, 0, stream>>>(counts, tot);
    k_scan2<<<B, NBT, 0, stream>>>(tot, base);
    k_scatter<<<B * CHB, 128, 0, stream>>>(buckets, counts, base, spos, undo, locsT);
    k_attn<<<B * NCH, 256, 0, stream>>>(q16, kn16, vhl, spos, locsT, so, slog);
    k_comb<<<B * S / 4, 256, 0, stream>>>(undo, slog, so, out);
}

// Round 4
// 131.208 us; speedup vs baseline: 2.5164x; 2.5164x over previous
//
#include <hip/hip_runtime.h>
#include <hip/hip_bf16.h>
#include <math.h>

// ---- problem constants (fixed by setup_inputs) ----
constexpr int B   = 4;
constexpr int S   = 4096;
constexpr int D   = 64;
constexpr int NH  = 8;        // hash rounds
constexpr int NB  = 64;       // buckets per hash
constexpr int NBT = 512;      // total buckets = NH*NB
constexpr int NI  = NH * S;   // items per batch = 32768
constexpr int NCH = 512;      // chunks per batch (of 64)
constexpr int CHB = 256;      // sort chunks per batch (of 128)

typedef __attribute__((ext_vector_type(8))) short bf16x8;
typedef __attribute__((ext_vector_type(4))) float f32x4;

__device__ __forceinline__ unsigned short bf_rne(float x) {
    unsigned u = __float_as_uint(x);
    u += 0x7fffu + ((u >> 16) & 1u);
    return (unsigned short)(u >> 16);
}
__device__ __forceinline__ float bf_tof(unsigned short h) {
    return __uint_as_float(((unsigned)h) << 16);
}

// ============================================================
// K0: prep — q16 = bf16(q/8), kn16 = bf16(k/||k||), vhl = (hi|lo<<16) of v
// grid: B*S/4 blocks, 256 threads (4 rows x 64 lanes)
// ============================================================
__global__ void k_prep(const float* __restrict__ q, const float* __restrict__ k,
                       const float* __restrict__ v, unsigned short* __restrict__ q16,
                       unsigned short* __restrict__ kn16, unsigned* __restrict__ vhl) {
    int row  = blockIdx.x * 4 + (threadIdx.x >> 6);
    int lane = threadIdx.x & 63;
    size_t idx = (size_t)row * 64 + lane;
    float kv = k[idx];
    float ss = kv * kv;
#pragma unroll
    for (int m = 1; m < 64; m <<= 1) ss += __shfl_xor(ss, m, 64);
    kn16[idx] = bf_rne(kv / sqrtf(ss));
    q16[idx]  = bf_rne(q[idx] * 0.125f);
    float vv = v[idx];
    unsigned short h = bf_rne(vv);
    unsigned short l = bf_rne(vv - bf_tof(h));
    vhl[idx] = (unsigned)h | ((unsigned)l << 16);
}

// ============================================================
// K1: LSH hashing (register-tiled GEMM + argmax) + fused histogram
// grid: B*NH*32 = 1024 blocks, 256 threads; block covers 128 tokens
// ============================================================
__global__ __launch_bounds__(256)
void k_hash(const float* __restrict__ q, const float* __restrict__ rot,
            int* __restrict__ buckets, int* __restrict__ counts) {
    int blk = blockIdx.x;
    int tko = blk & 31, h = (blk >> 5) & 7, b = blk >> 8;
    __shared__ __align__(16) float rs[64 * 36];   // [d][n] padded
    __shared__ int hist[64];
    if (threadIdx.x < 64) hist[threadIdx.x] = 0;
    for (int i = threadIdx.x; i < 2048; i += 256) {
        int nn = i & 31, d = i >> 5;
        rs[d * 36 + nn] = rot[(d * 8 + h) * 32 + nn];
    }
    __syncthreads();
    int tid = threadIdx.x;
    int ng = tid & 7, tg = tid >> 3;
    int t0 = tko * 128 + tg * 4;
    const float* qp = q + ((size_t)b * S + t0) * 64;
    float acc[4][4] = {};
    #pragma unroll 4
    for (int d4 = 0; d4 < 16; ++d4) {
        f32x4 r4[4];
        #pragma unroll
        for (int dd = 0; dd < 4; ++dd)
            r4[dd] = *(const f32x4*)(rs + (4 * d4 + dd) * 36 + 4 * ng);
        #pragma unroll
        for (int i = 0; i < 4; ++i) {
            f32x4 q4 = *(const f32x4*)(qp + i * 64 + d4 * 4);
            #pragma unroll
            for (int dd = 0; dd < 4; ++dd)
                #pragma unroll
                for (int c = 0; c < 4; ++c)
                    acc[i][c] += q4[dd] * r4[dd][c];
        }
    }
    #pragma unroll
    for (int i = 0; i < 4; ++i) {
        float vp = -3.402823466e38f, vn = -3.402823466e38f;
        int ip = 0, in_ = 0;
        #pragma unroll
        for (int c = 0; c < 4; ++c) {
            float a = acc[i][c]; int idx = 4 * ng + c;
            if (a > vp)  { vp = a;  ip = idx; }
            if (-a > vn) { vn = -a; in_ = idx; }
        }
        #pragma unroll
        for (int off = 1; off < 8; off <<= 1) {
            float ov = __shfl_xor(vp, off); int oi = __shfl_xor(ip, off);
            if (ov > vp || (ov == vp && oi < ip)) { vp = ov; ip = oi; }
            ov = __shfl_xor(vn, off); oi = __shfl_xor(in_, off);
            if (ov > vn || (ov == vn && oi < in_)) { vn = ov; in_ = oi; }
        }
        if (ng == 0) {
            int bi = (vn > vp) ? (in_ + 32) : ip;   // tie -> positive half
            buckets[b * NI + h * 4096 + t0 + i] = bi + h * NB;
            atomicAdd(&hist[bi], 1);
        }
    }
    __syncthreads();
    int cglob = h * 32 + tko;
    int* cw = counts + ((size_t)b * CHB + cglob) * NBT;
    for (int j = tid; j < NBT; j += 256) {
        int local = j - h * 64;
        cw[j] = (local >= 0 && local < 64) ? hist[local] : 0;
    }
}

// ============================================================
// K3a: per-(b,bucket) scan over 256 chunks (wave scan, 4/lane)
// grid: B*NBT = 2048 blocks, 64 threads
// ============================================================
__global__ void k_scan1(int* __restrict__ counts, int* __restrict__ tot) {
    int bkt = blockIdx.x & 511, b = blockIdx.x >> 9;
    int lane = threadIdx.x;
    size_t i0 = ((size_t)b * CHB + 4 * lane) * NBT + bkt;
    int v0 = counts[i0], v1 = counts[i0 + NBT], v2 = counts[i0 + 2 * NBT], v3 = counts[i0 + 3 * NBT];
    int s = v0 + v1 + v2 + v3;
    int incl = s;
    #pragma unroll
    for (int off = 1; off < 64; off <<= 1) {
        int t = __shfl_up(incl, off);
        if (lane >= off) incl += t;
    }
    int excl = incl - s;
    counts[i0]           = excl;
    counts[i0 + NBT]     = excl + v0;
    counts[i0 + 2 * NBT] = excl + v0 + v1;
    counts[i0 + 3 * NBT] = excl + v0 + v1 + v2;
    if (lane == 63) tot[b * NBT + bkt] = incl;
}

// ============================================================
// K3b: cross-bucket exclusive scan (per batch)
// ============================================================
__global__ void k_scan2(const int* __restrict__ tot, int* __restrict__ base) {
    int b = blockIdx.x, bkt = threadIdx.x;
    __shared__ int bufA[NBT], bufB[NBT];
    int run = tot[b * NBT + bkt];
    bufA[bkt] = run;
    __syncthreads();
    int* src = bufA; int* dst = bufB;
    for (int off = 1; off < NBT; off <<= 1) {
        int x = src[bkt] + ((bkt >= off) ? src[bkt - off] : 0);
        dst[bkt] = x;
        __syncthreads();
        int* tsw = src; src = dst; dst = tsw;
    }
    base[b * NBT + bkt] = src[bkt] - run;
}

// ============================================================
// K4: stable scatter — packed sorted meta + inverse perm + locsT
// grid: B*CHB = 1024 blocks, 128 threads
// ============================================================
__global__ void k_scatter(const int* __restrict__ buckets, const int* __restrict__ counts,
                          const int* __restrict__ base, int* __restrict__ spos,
                          int* __restrict__ undo, int* __restrict__ locsT) {
    int b = blockIdx.x >> 8, c = blockIdx.x & 255;
    __shared__ int bk_s[128];
    int i_loc  = threadIdx.x;
    int i_flat = c * 128 + i_loc;
    int bkt = buckets[b * NI + i_flat];
    bk_s[i_loc] = bkt;
    __syncthreads();
    int rank = 0;
    for (int j = 0; j < 128; ++j) {
        int vv = bk_s[j];
        rank += (j < i_loc && vv == bkt);
    }
    int pos = base[b * NBT + bkt] + counts[((size_t)b * CHB + c) * NBT + bkt] + rank;
    spos[b * NI + pos] = (i_flat & 4095) | (bkt << 12);   // t | bkt<<12
    undo[b * NI + i_flat] = pos;
    int h = i_flat >> 12, t = i_flat & 4095;
    locsT[(((size_t)b << 12) | t) * 8 + h] = bkt * NCH + (pos >> 6);
}

// ============================================================
// K6: chunked attention via MFMA (64 q rows x 128 keys, d=64)
//   LDS overlay: qs/ks (phase B/C) -> ph/pl + vh/vl (phase E/F).
//   V gathered from global AFTER the post-softmax barrier (no
//   cross-barrier register arrays -> no scratch spills).
//   54 KB LDS -> 3 blocks/CU (LDS-limited; VGPR ~92 allows it)
// ============================================================
__global__ __launch_bounds__(256, 2)
void k_attn(const unsigned short* __restrict__ q16, const unsigned short* __restrict__ kn16,
            const unsigned* __restrict__ vhl, const int* __restrict__ spos,
            const int* __restrict__ locsT, float* __restrict__ so,
            float* __restrict__ slog) {
    int n = blockIdx.x & 511, b = blockIdx.x >> 9;
    __shared__ __align__(16) char buf[54016];
    unsigned short* qs = (unsigned short*)buf;            // [64][72] bf16
    unsigned short* ks = (unsigned short*)(buf + 9216);   // [128][72] bf16
    unsigned short* ph = (unsigned short*)buf;            // [64][72] overlay
    unsigned short* pl = (unsigned short*)(buf + 9216);   // [64][72] overlay
    unsigned short* vh = (unsigned short*)(buf + 18432);  // [64][136] v^T hi
    unsigned short* vl = (unsigned short*)(buf + 35840);  // [64][136] v^T lo
    int* mq = (int*)(buf + 53248);                        // [64]  t|bkt<<12
    int* mk = (int*)(buf + 53504);                        // [128]

    int tid = threadIdx.x;
    int bni = b * NI;
    const unsigned short* q16b = q16 + ((size_t)b << 12) * 64;
    const unsigned short* kn16b = kn16 + ((size_t)b << 12) * 64;
    const unsigned* vhlb = vhl + ((size_t)b << 12) * 64;

    // ---- phase A: sorted-position metadata ----
    if (tid < 64) mq[tid] = spos[bni + n * 64 + tid];
    else if (tid < 192) {
        int z = tid - 64;
        int nn = (z < 64) ? n : ((n + 511) & 511);   // z>=64: previous chunk
        mk[z] = spos[bni + nn * 64 + (z & 63)];
    }
    __syncthreads();

    // ---- phase B: stage q/k tiles (pure 16B copies) ----
    #pragma unroll
    for (int it = 0; it < 2; ++it) {                  // q: 512 16B-chunks
        int i = it * 256 + tid;
        int row = i >> 3, c8 = i & 7;
        int t = mq[row] & 4095;
        uint4 val = *(const uint4*)(q16b + (size_t)t * 64 + c8 * 8);
        *(uint4*)(qs + row * 72 + c8 * 8) = val;
    }
    #pragma unroll
    for (int it = 0; it < 4; ++it) {                  // k: 1024 16B-chunks
        int i = it * 256 + tid;
        int row = i >> 3, c8 = i & 7;
        int t = mk[row] & 4095;
        uint4 val = *(const uint4*)(kn16b + (size_t)t * 64 + c8 * 8);
        *(uint4*)(ks + row * 72 + c8 * 8) = val;
    }
    __syncthreads();

    int li = tid & 15, hi4 = (tid >> 4) & 3, w = tid >> 6;

    // ---- phase C: QK^T via MFMA ----
    f32x4 sacc[8];
    {
        bf16x8 a0 = *(bf16x8*)(qs + (16 * w + li) * 72 + 8 * hi4);
        bf16x8 a1 = *(bf16x8*)(qs + (16 * w + li) * 72 + 32 + 8 * hi4);
        #pragma unroll
        for (int zt = 0; zt < 8; ++zt) {
            bf16x8 b0 = *(bf16x8*)(ks + (16 * zt + li) * 72 + 8 * hi4);
            bf16x8 b1 = *(bf16x8*)(ks + (16 * zt + li) * 72 + 32 + 8 * hi4);
            f32x4 c = {0.f, 0.f, 0.f, 0.f};
            c = __builtin_amdgcn_mfma_f32_16x16x32_bf16(a0, b0, c, 0, 0, 0);
            c = __builtin_amdgcn_mfma_f32_16x16x32_bf16(a1, b1, c, 0, 0, 0);
            sacc[zt] = c;
        }
    }

    // ---- phase D: masks + dup correction + softmax ----
    int tqr[4], bqr[4], lqr[4][8];
    #pragma unroll
    for (int j = 0; j < 4; ++j) {
        int R = 16 * w + 4 * hi4 + j;
        int m = mq[R];
        tqr[j] = m & 4095; bqr[j] = m >> 12;
        const int4* lp = (const int4*)(locsT + (((size_t)b << 12) | tqr[j]) * 8);
        int4 A = lp[0], Bv = lp[1];
        lqr[j][0] = A.x;  lqr[j][1] = A.y;  lqr[j][2] = A.z;  lqr[j][3] = A.w;
        lqr[j][4] = Bv.x; lqr[j][5] = Bv.y; lqr[j][6] = Bv.z; lqr[j][7] = Bv.w;
    }
    #pragma unroll
    for (int zt = 0; zt < 8; ++zt) {
        int z = 16 * zt + li;
        int mz = mk[z]; int tk = mz & 4095, bk = mz >> 12;
        const int4* lp = (const int4*)(locsT + (((size_t)b << 12) | tk) * 8);
        int4 A = lp[0], Bv = lp[1];
        int l1[8] = {A.x, A.y, A.z, A.w, Bv.x, Bv.y, Bv.z, Bv.w};
        int l2[8];
        #pragma unroll
        for (int h = 0; h < 8; ++h) l2[h] = (l1[h] & ~511) | ((l1[h] + 1) & 511);
        #pragma unroll
        for (int j = 0; j < 4; ++j) {
            float s = sacc[zt][j];
            if (tqr[j] == tk) s = -10000.0f;
            if (bqr[j] != bk) s = -3.402823466e38f;
            int dup = 0;
            #pragma unroll
            for (int h = 0; h < 8; ++h)
                dup += (int)(lqr[j][h] == l1[h]) + (int)(lqr[j][h] == l2[h]);
            s -= __logf((float)dup + 1e-9f);
            sacc[zt][j] = s;
        }
    }

    float inv[4];
    #pragma unroll
    for (int j = 0; j < 4; ++j) {
        float m = sacc[0][j];
        #pragma unroll
        for (int zt = 1; zt < 8; ++zt) m = fmaxf(m, sacc[zt][j]);
        #pragma unroll
        for (int off = 1; off < 16; off <<= 1) m = fmaxf(m, __shfl_xor(m, off));
        float sum = 0.f;
        #pragma unroll
        for (int zt = 0; zt < 8; ++zt) {
            float e = __expf(sacc[zt][j] - m);
            sacc[zt][j] = e; sum += e;
        }
        #pragma unroll
        for (int off = 1; off < 16; off <<= 1) sum += __shfl_xor(sum, off);
        float lse = m + __logf(sum);
        inv[j] = 1.0f / sum;
        if (li == 0) slog[bni + n * 64 + 16 * w + 4 * hi4 + j] = lse;
    }
    __syncthreads();   // all qs/ks reads done before overlays

    // ---- phase E0: gather V global->LDS (hi/lo split), write P half 0 ----
    #pragma unroll
    for (int it = 0; it < 16; ++it) {
        int i = it * 256 + tid;
        int d  = (i & 7) | (((i >> 8) & 7) << 3);
        int zp = ((i >> 3) & 31) | (((i >> 11) & 1) << 5);
        int t0 = mk[2 * zp] & 4095, t1 = mk[2 * zp + 1] & 4095;
        unsigned a = vhlb[(size_t)t0 * 64 + d];
        unsigned c = vhlb[(size_t)t1 * 64 + d];
        *(unsigned*)(vh + d * 136 + 2 * zp) = (a & 0xffffu) | (c << 16);
        *(unsigned*)(vl + d * 136 + 2 * zp) = (a >> 16) | (c & 0xffff0000u);
    }
    f32x4 oacc[4] = {{0,0,0,0},{0,0,0,0},{0,0,0,0},{0,0,0,0}};
    #pragma unroll
    for (int half = 0; half < 2; ++half) {
        #pragma unroll
        for (int zt4 = 0; zt4 < 4; ++zt4) {
            int zt = half * 4 + zt4;
            #pragma unroll
            for (int j = 0; j < 4; ++j) {
                float p  = sacc[zt][j] * inv[j];
                float po = __shfl_xor(p, 1);
                if ((li & 1) == 0) {
                    int R  = 16 * w + 4 * hi4 + j;
                    int zl = 16 * zt4 + li;   // even
                    unsigned short h0 = bf_rne(p), h1 = bf_rne(po);
                    *(unsigned*)(ph + R * 72 + zl) = (unsigned)h0 | ((unsigned)h1 << 16);
                    unsigned short g0 = bf_rne(p - bf_tof(h0)), g1 = bf_rne(po - bf_tof(h1));
                    *(unsigned*)(pl + R * 72 + zl) = (unsigned)g0 | ((unsigned)g1 << 16);
                }
            }
        }
        __syncthreads();
        #pragma unroll
        for (int step = 0; step < 2; ++step) {
            bf16x8 pa = *(bf16x8*)(ph + (16 * w + li) * 72 + 32 * step + 8 * hi4);
            bf16x8 pb = *(bf16x8*)(pl + (16 * w + li) * 72 + 32 * step + 8 * hi4);
            #pragma unroll
            for (int nt = 0; nt < 4; ++nt) {
                bf16x8 vb = *(bf16x8*)(vh + (16 * nt + li) * 136 + 64 * half + 32 * step + 8 * hi4);
                bf16x8 vc = *(bf16x8*)(vl + (16 * nt + li) * 136 + 64 * half + 32 * step + 8 * hi4);
                oacc[nt] = __builtin_amdgcn_mfma_f32_16x16x32_bf16(pa, vb, oacc[nt], 0, 0, 0);
                oacc[nt] = __builtin_amdgcn_mfma_f32_16x16x32_bf16(pb, vb, oacc[nt], 0, 0, 0);
                oacc[nt] = __builtin_amdgcn_mfma_f32_16x16x32_bf16(pa, vc, oacc[nt], 0, 0, 0);
            }
        }
        __syncthreads();
    }

    // ---- epilogue ----
    size_t ob = ((size_t)bni + n * 64) * 64;
    #pragma unroll
    for (int nt = 0; nt < 4; ++nt)
        #pragma unroll
        for (int j = 0; j < 4; ++j)
            so[ob + (size_t)(16 * w + 4 * hi4 + j) * 64 + 16 * nt + li] = oacc[nt][j];
}

// ============================================================
// K7: unsort + combine across hash rounds
// ============================================================
__global__ void k_comb(const int* __restrict__ undo, const float* __restrict__ slog,
                       const float* __restrict__ so, float* __restrict__ out) {
    int flatT = blockIdx.x * 4 + (threadIdx.x >> 6);
    int lane  = threadIdx.x & 63;
    int b = flatT >> 12, t = flatT & (S - 1);
    int ph[NH]; float lg[NH];
    float m = -3.402823466e38f;
#pragma unroll
    for (int h = 0; h < NH; ++h) {
        ph[h] = undo[b * NI + (h << 12) + t];
        lg[h] = slog[b * NI + ph[h]];
        m = fmaxf(m, lg[h]);
    }
    float sum = 0.f;
#pragma unroll
    for (int h = 0; h < NH; ++h) sum += __expf(lg[h] - m);
    float lse2 = m + __logf(sum);
    float o = 0.f;
#pragma unroll
    for (int h = 0; h < NH; ++h) {
        float wgt = __expf(lg[h] - lse2);
        o += wgt * so[((size_t)b * NI + ph[h]) * D + lane];
    }
    out[(size_t)flatT * D + lane] = o;
}

// ============================================================
extern "C" void kernel_launch(void* const* d_in, const int* in_sizes, int n_in,
                              void* d_out, int out_size, void* d_ws, size_t ws_size,
                              hipStream_t stream) {
    const float* q   = (const float*)d_in[0];
    const float* k   = (const float*)d_in[1];
    const float* v   = (const float*)d_in[2];
    const float* rot = (const float*)d_in[3];
    float* out = (float*)d_out;

    char* ws = (char*)d_ws;
    size_t off = 0;
    auto alloc = [&](size_t bytes) -> void* {
        void* p = ws + off;
        off += (bytes + 255) & ~(size_t)255;
        return p;
    };
    unsigned short* q16  = (unsigned short*)alloc((size_t)B * S * D * 2);
    unsigned short* kn16 = (unsigned short*)alloc((size_t)B * S * D * 2);
    unsigned*       vhl  = (unsigned*)alloc((size_t)B * S * D * 4);
    float* so      = (float*)alloc((size_t)B * NI * D * 4);
    float* slog    = (float*)alloc((size_t)B * NI * 4);
    int*   buckets = (int*)alloc((size_t)B * NI * 4);
    int*   counts  = (int*)alloc((size_t)B * CHB * NBT * 4);
    int*   tot     = (int*)alloc((size_t)B * NBT * 4);
    int*   base    = (int*)alloc((size_t)B * NBT * 4);
    int*   spos    = (int*)alloc((size_t)B * NI * 4);
    int*   undo    = (int*)alloc((size_t)B * NI * 4);
    int*   locsT   = (int*)alloc((size_t)B * S * NH * 4);

    k_prep<<<B * S / 4, 256, 0, stream>>>(q, k, v, q16, kn16, vhl);
    k_hash<<<1024, 256, 0, stream>>>(q, rot, buckets, counts);
    k_scan1<<<B * NBT, 64, 0, stream>>>(counts, tot);
    k_scan2<<<B, NBT, 0, stream>>>(tot, base);
    k_scatter<<<B * CHB, 128, 0, stream>>>(buckets, counts, base, spos, undo, locsT);
    k_attn<<<B * NCH, 256, 0, stream>>>(q16, kn16, vhl, spos, locsT, so, slog);
    k_comb<<<B * S / 4, 256, 0, stream>>>(undo, slog, so, out);
}